// Round 1
// baseline (468.357 us; speedup 1.0000x reference)
//
#include <hip/hip_runtime.h>
#include <math.h>

// Problem constants (fixed by setup_inputs): b=1, c=64, a=25, h=w=32
// E=128, L=1024, B=25, NUM_HEADS=8, Dh=16, FF=256, K_unfold=576
#define Lh 32
#define Lw 32
#define LL 1024          // Lh*Lw
#define BN 25            // b*a
#define EE 128
#define CC 64
#define NHD 8
#define DH 16
#define FFD 256
#define MROWS 25600      // LL*BN

// ---------------------------------------------------------------------------
// Kernel: transpose w_mlp [128][576] -> wt [576][128] (coalesced weight reads
// in the token kernel)
// ---------------------------------------------------------------------------
__global__ void k_transpose_wmlp(const float* __restrict__ w, float* __restrict__ wt) {
    int i = blockIdx.x * 256 + threadIdx.x;
    if (i < EE * 576) {
        int e = i / 576, k = i % 576;
        wt[k * EE + e] = w[i];
    }
}

// ---------------------------------------------------------------------------
// Kernel: fused token embed. Computes
//   tok  = sai2token(buffer, w_mlp)
//   xsum = sai2token(buffer + spa_position, w_mlp)   (= tok + pe, by linearity)
// Implicit im2col: tok[l,n,e] = sum_{ch,dy,dx} w[e, ch*9+dy*3+dx] *
//                               in[n, ch, y+dy-1, x+dx-1]
// Block = (n, y): 256 threads; thread (e = t&127, half = t>>7) computes 16 x's.
// ---------------------------------------------------------------------------
__global__ __launch_bounds__(256) void k_token(
    const float* __restrict__ buf, const float* __restrict__ spa,
    const float* __restrict__ wt, float* __restrict__ tok, float* __restrict__ xs)
{
    const int n = blockIdx.x;   // 0..24
    const int y = blockIdx.y;   // 0..31
    __shared__ float tb[16 * 3 * 34];   // [ch][dy][col], col = xx+1
    __shared__ float ts[16 * 3 * 34];
    const int t = threadIdx.x;
    const int e = t & 127;
    const int x0 = (t >> 7) * 16;

    float accT[16], accS[16];
#pragma unroll
    for (int i = 0; i < 16; i++) { accT[i] = 0.f; accS[i] = 0.f; }

    for (int ch0 = 0; ch0 < CC; ch0 += 16) {
        __syncthreads();
        for (int i = t; i < 16 * 3 * 34; i += 256) {
            int ch = i / 102; int rem = i % 102; int dy = rem / 34; int col = rem % 34;
            int yy = y + dy - 1; int xx = col - 1;
            float v = 0.f, s = 0.f;
            if (yy >= 0 && yy < Lh && xx >= 0 && xx < Lw) {
                int gi = ((ch0 + ch) * BN + n) * LL + yy * Lw + xx;
                v = buf[gi]; s = v + spa[gi];
            }
            tb[i] = v; ts[i] = s;
        }
        __syncthreads();

        for (int ch = 0; ch < 16; ch++) {
#pragma unroll
            for (int dy = 0; dy < 3; dy++) {
                const float* rowB = &tb[(ch * 3 + dy) * 34 + x0];
                const float* rowS = &ts[(ch * 3 + dy) * 34 + x0];
                float rb[18], rs[18];
#pragma unroll
                for (int i = 0; i < 18; i++) { rb[i] = rowB[i]; rs[i] = rowS[i]; }
                const float* wrow = &wt[(((ch0 + ch) * 9) + dy * 3) * EE + e];
                float w0 = wrow[0], w1 = wrow[EE], w2 = wrow[2 * EE];
#pragma unroll
                for (int xi = 0; xi < 16; xi++) {
                    accT[xi] += w0 * rb[xi] + w1 * rb[xi + 1] + w2 * rb[xi + 2];
                    accS[xi] += w0 * rs[xi] + w1 * rs[xi + 1] + w2 * rs[xi + 2];
                }
            }
        }
    }
#pragma unroll
    for (int xi = 0; xi < 16; xi++) {
        int l = y * Lw + x0 + xi;
        int o = (l * BN + n) * EE + e;
        tok[o] = accT[xi];
        xs[o]  = accS[xi];
    }
}

// ---------------------------------------------------------------------------
// Kernel: LayerNorm over E=128 per row. 4 waves/block, one row per wave.
// ---------------------------------------------------------------------------
__global__ __launch_bounds__(256) void k_ln(
    const float* __restrict__ in, const float* __restrict__ g,
    const float* __restrict__ b, float* __restrict__ out)
{
    int wave = threadIdx.x >> 6;
    int lane = threadIdx.x & 63;
    int row = blockIdx.x * 4 + wave;
    const float2 v = ((const float2*)(in + (size_t)row * EE))[lane];
    float s = v.x + v.y;
    float sq = v.x * v.x + v.y * v.y;
#pragma unroll
    for (int m = 1; m < 64; m <<= 1) {
        s  += __shfl_xor(s,  m, 64);
        sq += __shfl_xor(sq, m, 64);
    }
    float mean = s * (1.f / 128.f);
    float var  = sq * (1.f / 128.f) - mean * mean;
    float rstd = rsqrtf(var + 1e-5f);
    float2 gg = ((const float2*)g)[lane];
    float2 bb = ((const float2*)b)[lane];
    float2 o;
    o.x = (v.x - mean) * rstd * gg.x + bb.x;
    o.y = (v.y - mean) * rstd * gg.y + bb.y;
    ((float2*)(out + (size_t)row * EE))[lane] = o;
}

// ---------------------------------------------------------------------------
// Generic fp32 GEMM: C[M][N] = epi(A[M][K] @ B[N][K]^T)
// MODE 0: plain  MODE 1: relu  MODE 2: +R (residual, same layout as C)
// MODE 3: conv scatter: row m=(l*25+n_b) -> C[(col*25+n_b)*1024 + l]
// 64x64 tile, BK=32, 256 threads, 4x4 per thread.
// ---------------------------------------------------------------------------
template <int MODE>
__global__ __launch_bounds__(256) void k_gemm(
    const float* __restrict__ A, const float* __restrict__ Bm,
    const float* __restrict__ R, float* __restrict__ C,
    int M, int N, int K)
{
    __shared__ float As[32][68];
    __shared__ float Bs[32][68];
    const int m0 = blockIdx.x * 64;
    const int n0 = blockIdx.y * 64;
    const int tid = threadIdx.x;
    const int tx = tid & 15;
    const int ty = tid >> 4;
    float acc[4][4];
#pragma unroll
    for (int i = 0; i < 4; i++)
#pragma unroll
        for (int j = 0; j < 4; j++) acc[i][j] = 0.f;

    for (int k0 = 0; k0 < K; k0 += 32) {
        __syncthreads();
#pragma unroll
        for (int rep = 0; rep < 2; rep++) {
            int i = tid + rep * 256;       // 0..511
            int r = i >> 3;                // 0..63
            int c4 = (i & 7) << 2;         // 0,4,...,28
            const float4 va = *(const float4*)(A + (size_t)(m0 + r) * K + k0 + c4);
            As[c4 + 0][r] = va.x; As[c4 + 1][r] = va.y;
            As[c4 + 2][r] = va.z; As[c4 + 3][r] = va.w;
            const float4 vb = *(const float4*)(Bm + (size_t)(n0 + r) * K + k0 + c4);
            Bs[c4 + 0][r] = vb.x; Bs[c4 + 1][r] = vb.y;
            Bs[c4 + 2][r] = vb.z; Bs[c4 + 3][r] = vb.w;
        }
        __syncthreads();
#pragma unroll
        for (int k = 0; k < 32; k++) {
            const float4 a = *(const float4*)&As[k][ty << 2];
            const float4 b = *(const float4*)&Bs[k][tx << 2];
            acc[0][0] = fmaf(a.x, b.x, acc[0][0]); acc[0][1] = fmaf(a.x, b.y, acc[0][1]);
            acc[0][2] = fmaf(a.x, b.z, acc[0][2]); acc[0][3] = fmaf(a.x, b.w, acc[0][3]);
            acc[1][0] = fmaf(a.y, b.x, acc[1][0]); acc[1][1] = fmaf(a.y, b.y, acc[1][1]);
            acc[1][2] = fmaf(a.y, b.z, acc[1][2]); acc[1][3] = fmaf(a.y, b.w, acc[1][3]);
            acc[2][0] = fmaf(a.z, b.x, acc[2][0]); acc[2][1] = fmaf(a.z, b.y, acc[2][1]);
            acc[2][2] = fmaf(a.z, b.z, acc[2][2]); acc[2][3] = fmaf(a.z, b.w, acc[2][3]);
            acc[3][0] = fmaf(a.w, b.x, acc[3][0]); acc[3][1] = fmaf(a.w, b.y, acc[3][1]);
            acc[3][2] = fmaf(a.w, b.z, acc[3][2]); acc[3][3] = fmaf(a.w, b.w, acc[3][3]);
        }
    }

    const int m = m0 + (ty << 2);
    const int n = n0 + (tx << 2);
    if (MODE == 3) {
#pragma unroll
        for (int i = 0; i < 4; i++) {
            int mm = m + i;
            int l = mm / 25, bn = mm % 25;
#pragma unroll
            for (int j = 0; j < 4; j++) {
                C[(size_t)((n + j) * 25 + bn) * 1024 + l] = acc[i][j];
            }
        }
    } else {
#pragma unroll
        for (int i = 0; i < 4; i++) {
            float4 v = make_float4(acc[i][0], acc[i][1], acc[i][2], acc[i][3]);
            if (MODE == 1) {
                v.x = fmaxf(v.x, 0.f); v.y = fmaxf(v.y, 0.f);
                v.z = fmaxf(v.z, 0.f); v.w = fmaxf(v.w, 0.f);
            }
            if (MODE == 2) {
                const float4 r = *(const float4*)(R + (size_t)(m + i) * N + n);
                v.x += r.x; v.y += r.y; v.z += r.z; v.w += r.w;
            }
            *(float4*)(C + (size_t)(m + i) * N + n) = v;
        }
    }
}

// ---------------------------------------------------------------------------
// Kernel: local-window attention (5x5, mask = -inf outside).
// Block = (y, n*8+h). 256 threads; 8 threads per query x (32 queries/row).
// Stages K,V rows y-2..y+2 and Q row y in LDS. Softmax over <=25 valid keys.
// ---------------------------------------------------------------------------
__global__ __launch_bounds__(256) void k_attn(
    const float* __restrict__ Q, const float* __restrict__ Kb,
    const float* __restrict__ V, float* __restrict__ O)
{
    const int y = blockIdx.x;
    const int n = blockIdx.y / NHD;
    const int h = blockIdx.y % NHD;
    __shared__ float Ks[5 * 32 * 16];
    __shared__ float Vs[5 * 32 * 16];
    __shared__ float Qs[32 * 16];
    const int t = threadIdx.x;

    for (int i = t; i < 640; i += 256) {      // 5*32*16/4 float4s
        int r = i >> 7;
        int rem = i & 127;
        int x = rem >> 2;
        int d4 = (rem & 3) * 4;
        int yy = y - 2 + r;
        float4 kv = make_float4(0, 0, 0, 0), vv = make_float4(0, 0, 0, 0);
        if (yy >= 0 && yy < Lh) {
            int gi = ((yy * Lw + x) * BN + n) * EE + h * DH + d4;
            kv = *(const float4*)(Kb + gi);
            vv = *(const float4*)(V + gi);
        }
        *(float4*)(Ks + i * 4) = kv;
        *(float4*)(Vs + i * 4) = vv;
    }
    if (t < 128) {
        int x = t >> 2; int d4 = (t & 3) * 4;
        int gi = ((y * Lw + x) * BN + n) * EE + h * DH + d4;
        *(float4*)(Qs + t * 4) = *(const float4*)(Q + gi);
    }
    __syncthreads();

    const int qx = t >> 3;     // query x in row
    const int sub = t & 7;     // 8 lanes per query
    float q[DH];
#pragma unroll
    for (int d = 0; d < DH; d++) q[d] = Qs[qx * DH + d];

    float sc[4]; bool val[4]; int kr[4], kx[4];
    float mx = -1e30f;
#pragma unroll
    for (int s = 0; s < 4; s++) {
        int kk = sub + 8 * s;
        sc[s] = -1e30f; val[s] = false; kr[s] = 0; kx[s] = 0;
        if (kk < 25) {
            int r = kk / 5;
            int xx = (kk % 5) - 2 + qx;
            int yy = y - 2 + r;
            if (yy >= 0 && yy < Lh && xx >= 0 && xx < Lw) {
                val[s] = true; kr[s] = r; kx[s] = xx;
                const float* kp = Ks + (r * 32 + xx) * DH;
                float d0 = 0.f;
#pragma unroll
                for (int d = 0; d < DH; d++) d0 += q[d] * kp[d];
                sc[s] = d0 * 0.25f;   // 1/sqrt(16)
                mx = fmaxf(mx, sc[s]);
            }
        }
    }
#pragma unroll
    for (int m = 1; m < 8; m <<= 1) mx = fmaxf(mx, __shfl_xor(mx, m, 64));
    float p[4]; float lsum = 0.f;
#pragma unroll
    for (int s = 0; s < 4; s++) { p[s] = val[s] ? __expf(sc[s] - mx) : 0.f; lsum += p[s]; }
#pragma unroll
    for (int m = 1; m < 8; m <<= 1) lsum += __shfl_xor(lsum, m, 64);
    const float inv = 1.f / lsum;

    float out[DH];
#pragma unroll
    for (int d = 0; d < DH; d++) out[d] = 0.f;
#pragma unroll
    for (int s = 0; s < 4; s++) {
        if (val[s]) {
            float a = p[s] * inv;
            const float* vp = Vs + (kr[s] * 32 + kx[s]) * DH;
#pragma unroll
            for (int d = 0; d < DH; d++) out[d] += a * vp[d];
        }
    }
#pragma unroll
    for (int d = 0; d < DH; d++)
#pragma unroll
        for (int m = 1; m < 8; m <<= 1) out[d] += __shfl_xor(out[d], m, 64);

    const int l = y * Lw + qx;
    const int o = (l * BN + n) * EE + h * DH + sub * 2;
    O[o]     = out[sub * 2];
    O[o + 1] = out[sub * 2 + 1];
}

// ---------------------------------------------------------------------------
// Launch
// ---------------------------------------------------------------------------
extern "C" void kernel_launch(void* const* d_in, const int* in_sizes, int n_in,
                              void* d_out, int out_size, void* d_ws, size_t ws_size,
                              hipStream_t stream)
{
    const float* buffer   = (const float*)d_in[0];
    const float* spa      = (const float*)d_in[1];
    const float* w_mlp    = (const float*)d_in[2];
    const float* ln1_g    = (const float*)d_in[3];
    const float* ln1_b    = (const float*)d_in[4];
    const float* in_proj  = (const float*)d_in[5];
    const float* out_proj = (const float*)d_in[6];
    const float* ln2_g    = (const float*)d_in[7];
    const float* ln2_b    = (const float*)d_in[8];
    const float* ff_w1    = (const float*)d_in[9];
    const float* ff_w2    = (const float*)d_in[10];
    const float* conv_w   = (const float*)d_in[11];
    float* out = (float*)d_out;

    float* ws = (float*)d_ws;
    const size_t SZ = (size_t)MROWS * EE;   // 3,276,800 floats
    float* TOK = ws;              // tok (residual stream)
    float* X   = ws + SZ;         // tok+pe -> ln1 -> attn_out -> ln2 out
    float* Qb  = ws + 2 * SZ;     // q  (later: ff lower half)
    float* Kb  = ws + 3 * SZ;     // k  (later: ff upper half)
    float* Vb  = ws + 4 * SZ;     // v
    float* WT  = ws + 5 * SZ;     // transposed w_mlp [576][128]
    float* FF  = Qb;              // 25600 x 256 spans Qb..Kb regions

    // 1. transpose w_mlp
    k_transpose_wmlp<<<dim3((EE * 576 + 255) / 256), 256, 0, stream>>>(w_mlp, WT);
    // 2. token embed: TOK = sai2token(buffer), X = sai2token(buffer+spa)
    k_token<<<dim3(BN, Lh), 256, 0, stream>>>(buffer, spa, WT, TOK, X);
    // 3. ln1 in place on X
    k_ln<<<dim3(MROWS / 4), 256, 0, stream>>>(X, ln1_g, ln1_b, X);
    // 4. q, k from X; v from TOK
    k_gemm<0><<<dim3(MROWS / 64, 2), 256, 0, stream>>>(X,   in_proj,              nullptr, Qb, MROWS, EE, EE);
    k_gemm<0><<<dim3(MROWS / 64, 2), 256, 0, stream>>>(X,   in_proj + EE * EE,    nullptr, Kb, MROWS, EE, EE);
    k_gemm<0><<<dim3(MROWS / 64, 2), 256, 0, stream>>>(TOK, in_proj + 2 * EE * EE, nullptr, Vb, MROWS, EE, EE);
    // 5. local attention -> X (X free after q,k)
    k_attn<<<dim3(Lh, BN * NHD), 256, 0, stream>>>(Qb, Kb, Vb, X);
    // 6. out_proj + residual: TOK = X @ Wo^T + TOK
    k_gemm<2><<<dim3(MROWS / 64, 2), 256, 0, stream>>>(X, out_proj, TOK, TOK, MROWS, EE, EE);
    // 7. ln2: X = LN(TOK)
    k_ln<<<dim3(MROWS / 4), 256, 0, stream>>>(TOK, ln2_g, ln2_b, X);
    // 8. ff1 + relu: FF = relu(X @ W1^T)   (N=256)
    k_gemm<1><<<dim3(MROWS / 64, 4), 256, 0, stream>>>(X, ff_w1, nullptr, FF, MROWS, FFD, EE);
    // 9. ff2 + residual: TOK = FF @ W2^T + TOK   (K=256)
    k_gemm<2><<<dim3(MROWS / 64, 2), 256, 0, stream>>>(FF, ff_w2, TOK, TOK, MROWS, EE, FFD);
    // 10. conv + output scatter: out[(o*25+n)*1024 + l] = TOK @ conv_w^T
    k_gemm<3><<<dim3(MROWS / 64, 1), 256, 0, stream>>>(TOK, conv_w, nullptr, out, MROWS, CC, EE);
}

// Round 2
// 224.095 us; speedup vs baseline: 2.0900x; 2.0900x over previous
//
#include <hip/hip_runtime.h>
#include <math.h>

// SpaTrans on MI355X. R2: all GEMM-shaped work moved to bf16 MFMA 16x16x32.
// b=1, c=64, a=25, h=w=32 -> L=1024, B=25, E=128, heads=8, Dh=16, FF=256.
#define Lh 32
#define Lw 32
#define LL 1024
#define BN 25
#define EE 128
#define CC 64
#define NHD 8
#define DH 16
#define FFD 256
#define MROWS 25600

typedef __attribute__((ext_vector_type(8))) short short8;   // 8 bf16 = 4 VGPRs (MFMA A/B frag)
typedef __attribute__((ext_vector_type(4))) float f32x4;    // MFMA C/D frag

// fp32 -> bf16 RNE
__device__ inline ushort f2b(float x) {
    union { float f; unsigned u; } v; v.f = x;
    unsigned r = (v.u + 0x7fffu + ((v.u >> 16) & 1u)) >> 16;
    return (ushort)r;
}
__device__ inline float b2f(ushort u) {
    union { unsigned u; float f; } v; v.u = ((unsigned)u) << 16;
    return v.f;
}
__device__ inline void unpack8(uint4 p, float* dst) {
    unsigned vals[4] = { p.x, p.y, p.z, p.w };
#pragma unroll
    for (int i = 0; i < 4; i++) {
        union { unsigned u; float f; } lo, hi;
        lo.u = (vals[i] & 0xffffu) << 16;
        hi.u = vals[i] & 0xffff0000u;
        dst[2 * i] = lo.f; dst[2 * i + 1] = hi.f;
    }
}

// ---------------------------------------------------------------------------
// Weight prep: cast all weights to bf16; w_mlp is K-reordered (k' = tap*64+ch,
// orig k = ch*9+tap) so each K=32 MFMA chunk stays inside one tap.
// Wb layout (ushorts): W2[128][576] | WQK[256][128] | WV[128][128] |
//                      WO[128][128] | W1[256][128] | W2f[128][256] | WC[64][128]
// ---------------------------------------------------------------------------
#define OFF_W2  0
#define OFF_WQK 73728
#define OFF_WV  106496
#define OFF_WO  122880
#define OFF_W1  139264
#define OFF_W2F 172032
#define OFF_WC  204800
#define W_TOTAL 212992

__global__ __launch_bounds__(256) void k_prep_w(
    const float* __restrict__ w_mlp, const float* __restrict__ in_proj,
    const float* __restrict__ out_proj, const float* __restrict__ ff_w1,
    const float* __restrict__ ff_w2, const float* __restrict__ conv_w,
    ushort* __restrict__ Wb)
{
    int i = blockIdx.x * 256 + threadIdx.x;
    if (i >= W_TOTAL) return;
    if (i < 73728) {
        int e = i / 576, k = i - e * 576;
        int tap = k >> 6, ch = k & 63;
        Wb[OFF_W2 + i] = f2b(w_mlp[e * 576 + ch * 9 + tap]);
        return;
    }
    i -= 73728;
    if (i < 32768) { Wb[OFF_WQK + i] = f2b(in_proj[i]); return; }
    i -= 32768;
    if (i < 16384) { Wb[OFF_WV + i] = f2b(in_proj[32768 + i]); return; }
    i -= 16384;
    if (i < 16384) { Wb[OFF_WO + i] = f2b(out_proj[i]); return; }
    i -= 16384;
    if (i < 32768) { Wb[OFF_W1 + i] = f2b(ff_w1[i]); return; }
    i -= 32768;
    if (i < 32768) { Wb[OFF_W2F + i] = f2b(ff_w2[i]); return; }
    i -= 32768;
    Wb[OFF_WC + i] = f2b(conv_w[i]);
}

// ---------------------------------------------------------------------------
// Input prep: buf [ch][n][y][x] fp32 -> T [n][y][x][ch] bf16, S = bf16(buf+spa)
// Block (n,y): LDS transpose of a 64ch x 32x tile.
// ---------------------------------------------------------------------------
__global__ __launch_bounds__(256) void k_prep_in(
    const float* __restrict__ buf, const float* __restrict__ spa,
    ushort* __restrict__ T, ushort* __restrict__ S)
{
    const int n = blockIdx.x, y = blockIdx.y;
    __shared__ float t0[64][33];
    __shared__ float t1[64][33];
    const int t = threadIdx.x;
    {
        int ch = t >> 2, x8 = (t & 3) * 8;
        const float* p = buf + ((size_t)(ch * BN + n) * LL + y * Lw + x8);
        const float* q = spa + ((size_t)(ch * BN + n) * LL + y * Lw + x8);
        float4 a0 = ((const float4*)p)[0], a1 = ((const float4*)p)[1];
        float4 b0 = ((const float4*)q)[0], b1 = ((const float4*)q)[1];
        float* d0 = &t0[ch][x8];
        float* d1 = &t1[ch][x8];
        d0[0] = a0.x; d0[1] = a0.y; d0[2] = a0.z; d0[3] = a0.w;
        d0[4] = a1.x; d0[5] = a1.y; d0[6] = a1.z; d0[7] = a1.w;
        d1[0] = a0.x + b0.x; d1[1] = a0.y + b0.y; d1[2] = a0.z + b0.z; d1[3] = a0.w + b0.w;
        d1[4] = a1.x + b1.x; d1[5] = a1.y + b1.y; d1[6] = a1.z + b1.z; d1[7] = a1.w + b1.w;
    }
    __syncthreads();
    {
        int x = t >> 3, c8 = (t & 7) * 8;
        union { ushort u[8]; uint4 v; } o0, o1;
#pragma unroll
        for (int j = 0; j < 8; j++) { o0.u[j] = f2b(t0[c8 + j][x]); o1.u[j] = f2b(t1[c8 + j][x]); }
        size_t base = (((size_t)n * Lh + y) * Lw + x) * 64 + c8;
        *(uint4*)(T + base) = o0.v;
        *(uint4*)(S + base) = o1.v;
    }
}

// ---------------------------------------------------------------------------
// Token embed via MFMA: for block (n,y) compute tok[l,n,:] and xs[l,n,:] for
// all 32 x.  A-tile (3 shifted rows of [x][ch]) staged in LDS (stride 72:
// 2-way bank aliasing = free).  B (W2) fragments read from global (L1-hot).
// Wave w owns e-slice [w*32, w*32+32).  18 K-chunks (9 taps x 2 ch-halves).
// ---------------------------------------------------------------------------
__global__ __launch_bounds__(256) void k_token_mfma(
    const ushort* __restrict__ T, const ushort* __restrict__ S,
    const ushort* __restrict__ W2, float* __restrict__ tok, float* __restrict__ xs)
{
    const int n = blockIdx.x, y = blockIdx.y;
    __shared__ ushort At[3 * 34 * 72];
    __shared__ ushort As_[3 * 34 * 72];
    const int t = threadIdx.x;
    const uint4 z = make_uint4(0, 0, 0, 0);

    {
        int x = t >> 3, c8 = (t & 7) * 8;
#pragma unroll
        for (int dy = 0; dy < 3; dy++) {
            int yy = y + dy - 1;
            uint4 va = z, vs = z;
            if (yy >= 0 && yy < Lh) {
                size_t gi = (((size_t)n * Lh + yy) * Lw + x) * 64 + c8;
                va = *(const uint4*)(T + gi);
                vs = *(const uint4*)(S + gi);
            }
            *(uint4*)(At + (dy * 34 + x + 1) * 72 + c8) = va;
            *(uint4*)(As_ + (dy * 34 + x + 1) * 72 + c8) = vs;
        }
        if (t < 48) {  // zero pad columns (x=-1 and x=32)
            int dy = t / 16, rem = t % 16;
            int colp = (rem >> 3) * 33, c8p = (rem & 7) * 8;
            *(uint4*)(At + (dy * 34 + colp) * 72 + c8p) = z;
            *(uint4*)(As_ + (dy * 34 + colp) * 72 + c8p) = z;
        }
    }
    __syncthreads();

    const int w = t >> 6, lane = t & 63;
    const int col = lane & 15, quad = lane >> 4;
    f32x4 accT[2][2] = {}, accS[2][2] = {};

    for (int tap = 0; tap < 9; tap++) {
        int dy = tap / 3, dx = tap % 3;
#pragma unroll
        for (int cc = 0; cc < 2; cc++) {
            int kg = tap * 64 + cc * 32 + quad * 8;
            short8 b0 = *(const short8*)(W2 + (size_t)(w * 32 + col) * 576 + kg);
            short8 b1 = *(const short8*)(W2 + (size_t)(w * 32 + 16 + col) * 576 + kg);
            int abase = (dy * 34 + col + dx) * 72 + cc * 32 + quad * 8;
            short8 aT0 = *(const short8*)(At + abase);
            short8 aT1 = *(const short8*)(At + abase + 16 * 72);
            short8 aS0 = *(const short8*)(As_ + abase);
            short8 aS1 = *(const short8*)(As_ + abase + 16 * 72);
            accT[0][0] = __builtin_amdgcn_mfma_f32_16x16x32_bf16(aT0, b0, accT[0][0], 0, 0, 0);
            accT[0][1] = __builtin_amdgcn_mfma_f32_16x16x32_bf16(aT0, b1, accT[0][1], 0, 0, 0);
            accT[1][0] = __builtin_amdgcn_mfma_f32_16x16x32_bf16(aT1, b0, accT[1][0], 0, 0, 0);
            accT[1][1] = __builtin_amdgcn_mfma_f32_16x16x32_bf16(aT1, b1, accT[1][1], 0, 0, 0);
            accS[0][0] = __builtin_amdgcn_mfma_f32_16x16x32_bf16(aS0, b0, accS[0][0], 0, 0, 0);
            accS[0][1] = __builtin_amdgcn_mfma_f32_16x16x32_bf16(aS0, b1, accS[0][1], 0, 0, 0);
            accS[1][0] = __builtin_amdgcn_mfma_f32_16x16x32_bf16(aS1, b0, accS[1][0], 0, 0, 0);
            accS[1][1] = __builtin_amdgcn_mfma_f32_16x16x32_bf16(aS1, b1, accS[1][1], 0, 0, 0);
        }
    }

#pragma unroll
    for (int mi = 0; mi < 2; mi++)
#pragma unroll
        for (int r = 0; r < 4; r++) {
            int x = mi * 16 + quad * 4 + r;
            size_t rowo = ((size_t)(y * Lw + x) * BN + n) * EE;
#pragma unroll
            for (int ni = 0; ni < 2; ni++) {
                int e = w * 32 + ni * 16 + col;
                tok[rowo + e] = accT[mi][ni][r];
                xs[rowo + e]  = accS[mi][ni][r];
            }
        }
}

// ---------------------------------------------------------------------------
// LayerNorm over E=128, bf16 output. One row per wave, 4 waves/block.
// ---------------------------------------------------------------------------
__global__ __launch_bounds__(256) void k_ln_bf(
    const float* __restrict__ in, const float* __restrict__ g,
    const float* __restrict__ b, ushort* __restrict__ out)
{
    int wave = threadIdx.x >> 6, lane = threadIdx.x & 63;
    int row = blockIdx.x * 4 + wave;
    const float2 v = ((const float2*)(in + (size_t)row * EE))[lane];
    float s = v.x + v.y, sq = v.x * v.x + v.y * v.y;
#pragma unroll
    for (int m = 1; m < 64; m <<= 1) {
        s  += __shfl_xor(s,  m, 64);
        sq += __shfl_xor(sq, m, 64);
    }
    float mean = s * (1.f / 128.f);
    float var  = sq * (1.f / 128.f) - mean * mean;
    float rstd = rsqrtf(var + 1e-5f);
    float2 gg = ((const float2*)g)[lane];
    float2 bb = ((const float2*)b)[lane];
    float ox = (v.x - mean) * rstd * gg.x + bb.x;
    float oy = (v.y - mean) * rstd * gg.y + bb.y;
    ((unsigned*)(out + (size_t)row * EE))[lane] = (unsigned)f2b(ox) | ((unsigned)f2b(oy) << 16);
}

// ---------------------------------------------------------------------------
// MFMA GEMM: C = epi(A[M][K] @ B[N][K]^T).  BM=128, BN=64, BK=32, 4 waves.
// ABF: A is bf16 (else fp32, cast during staging).  B always bf16.
// MODE 1: relu -> bf16 C | 2: +R -> fp32 C | 3: conv scatter fp32 | 4: bf16 C
// ---------------------------------------------------------------------------
template <int MODE, bool ABF>
__global__ __launch_bounds__(256) void k_mgemm(
    const void* __restrict__ Ap, const ushort* __restrict__ Bw,
    const float* __restrict__ R, void* __restrict__ Cp,
    int M, int N, int K)
{
    __shared__ ushort As[128 * 40];
    __shared__ ushort Bs[64 * 40];
    const int m0 = blockIdx.x * 128, n0 = blockIdx.y * 64;
    const int t = threadIdx.x, w = t >> 6, lane = t & 63;
    const int col = lane & 15, quad = lane >> 4;
    f32x4 acc[2][4] = {};

    for (int k0 = 0; k0 < K; k0 += 32) {
        __syncthreads();
        {   // stage B tile 64x32
            int nn = t >> 2, k8 = (t & 3) * 8;
            *(uint4*)(Bs + nn * 40 + k8) = *(const uint4*)(Bw + (size_t)(n0 + nn) * K + k0 + k8);
        }
        {   // stage A tile 128x32
            int r = t >> 1, k16 = (t & 1) * 16;
            if (ABF) {
                const ushort* A = (const ushort*)Ap;
                const uint4* p = (const uint4*)(A + (size_t)(m0 + r) * K + k0 + k16);
                *(uint4*)(As + r * 40 + k16) = p[0];
                *(uint4*)(As + r * 40 + k16 + 8) = p[1];
            } else {
                const float* A = (const float*)Ap;
                const float4* p = (const float4*)(A + (size_t)(m0 + r) * K + k0 + k16);
                float4 f0 = p[0], f1 = p[1], f2 = p[2], f3 = p[3];
                union { ushort u[8]; uint4 v; } o0, o1;
                o0.u[0] = f2b(f0.x); o0.u[1] = f2b(f0.y); o0.u[2] = f2b(f0.z); o0.u[3] = f2b(f0.w);
                o0.u[4] = f2b(f1.x); o0.u[5] = f2b(f1.y); o0.u[6] = f2b(f1.z); o0.u[7] = f2b(f1.w);
                o1.u[0] = f2b(f2.x); o1.u[1] = f2b(f2.y); o1.u[2] = f2b(f2.z); o1.u[3] = f2b(f2.w);
                o1.u[4] = f2b(f3.x); o1.u[5] = f2b(f3.y); o1.u[6] = f2b(f3.z); o1.u[7] = f2b(f3.w);
                *(uint4*)(As + r * 40 + k16) = o0.v;
                *(uint4*)(As + r * 40 + k16 + 8) = o1.v;
            }
        }
        __syncthreads();
        short8 a0 = *(const short8*)(As + (w * 32 + col) * 40 + quad * 8);
        short8 a1 = *(const short8*)(As + (w * 32 + 16 + col) * 40 + quad * 8);
#pragma unroll
        for (int ni = 0; ni < 4; ni++) {
            short8 bf = *(const short8*)(Bs + (ni * 16 + col) * 40 + quad * 8);
            acc[0][ni] = __builtin_amdgcn_mfma_f32_16x16x32_bf16(a0, bf, acc[0][ni], 0, 0, 0);
            acc[1][ni] = __builtin_amdgcn_mfma_f32_16x16x32_bf16(a1, bf, acc[1][ni], 0, 0, 0);
        }
    }

#pragma unroll
    for (int mi = 0; mi < 2; mi++)
#pragma unroll
        for (int r = 0; r < 4; r++) {
            int m = m0 + w * 32 + mi * 16 + quad * 4 + r;
#pragma unroll
            for (int ni = 0; ni < 4; ni++) {
                int nn = n0 + ni * 16 + col;
                float v = acc[mi][ni][r];
                if (MODE == 1) {
                    ((ushort*)Cp)[(size_t)m * N + nn] = f2b(fmaxf(v, 0.f));
                } else if (MODE == 2) {
                    ((float*)Cp)[(size_t)m * N + nn] = v + R[(size_t)m * N + nn];
                } else if (MODE == 3) {
                    int l = m / 25, bn = m - l * 25;
                    ((float*)Cp)[((size_t)nn * 25 + bn) * 1024 + l] = v;
                } else {
                    ((ushort*)Cp)[(size_t)m * N + nn] = f2b(v);
                }
            }
        }
}

// ---------------------------------------------------------------------------
// Local-window attention (5x5). Q,K packed in QK bf16 [m][256] (K at +128),
// V bf16 [m][128].  Block = (y, n*8+h).  Output bf16.
// ---------------------------------------------------------------------------
__global__ __launch_bounds__(256) void k_attn(
    const ushort* __restrict__ QK, const ushort* __restrict__ Vb,
    ushort* __restrict__ O)
{
    const int y = blockIdx.x;
    const int n = blockIdx.y / NHD;
    const int h = blockIdx.y % NHD;
    __shared__ float Ks[5 * 32 * 16];
    __shared__ float Vs[5 * 32 * 16];
    __shared__ float Qs[32 * 16];
    const int t = threadIdx.x;

    for (int i = t; i < 320; i += 256) {   // 5 rows x 32 x x 2 chunks of 8 d
        int r = i >> 6, rem = i & 63, x = rem >> 1, d8 = (rem & 1) * 8;
        int yy = y - 2 + r;
        float kf[8] = {0, 0, 0, 0, 0, 0, 0, 0}, vf[8] = {0, 0, 0, 0, 0, 0, 0, 0};
        if (yy >= 0 && yy < Lh) {
            size_t base = (size_t)((yy * Lw + x) * BN + n);
            unpack8(*(const uint4*)(QK + base * 256 + 128 + h * DH + d8), kf);
            unpack8(*(const uint4*)(Vb + base * 128 + h * DH + d8), vf);
        }
        float* kd = Ks + (r * 32 + x) * DH + d8;
        float* vd = Vs + (r * 32 + x) * DH + d8;
#pragma unroll
        for (int j = 0; j < 8; j++) { kd[j] = kf[j]; vd[j] = vf[j]; }
    }
    if (t < 64) {
        int x = t >> 1, d8 = (t & 1) * 8;
        float qf[8];
        unpack8(*(const uint4*)(QK + (size_t)((y * Lw + x) * BN + n) * 256 + h * DH + d8), qf);
        float* qd = Qs + x * DH + d8;
#pragma unroll
        for (int j = 0; j < 8; j++) qd[j] = qf[j];
    }
    __syncthreads();

    const int qx = t >> 3, sub = t & 7;
    float q[DH];
#pragma unroll
    for (int d = 0; d < DH; d++) q[d] = Qs[qx * DH + d];

    float sc[4]; bool val[4]; int kr[4], kx[4];
    float mx = -1e30f;
#pragma unroll
    for (int s = 0; s < 4; s++) {
        int kk = sub + 8 * s;
        sc[s] = -1e30f; val[s] = false; kr[s] = 0; kx[s] = 0;
        if (kk < 25) {
            int r = kk / 5;
            int xx = (kk % 5) - 2 + qx;
            int yy = y - 2 + r;
            if (yy >= 0 && yy < Lh && xx >= 0 && xx < Lw) {
                val[s] = true; kr[s] = r; kx[s] = xx;
                const float* kp = Ks + (r * 32 + xx) * DH;
                float d0 = 0.f;
#pragma unroll
                for (int d = 0; d < DH; d++) d0 += q[d] * kp[d];
                sc[s] = d0 * 0.25f;
                mx = fmaxf(mx, sc[s]);
            }
        }
    }
#pragma unroll
    for (int m = 1; m < 8; m <<= 1) mx = fmaxf(mx, __shfl_xor(mx, m, 64));
    float p[4]; float lsum = 0.f;
#pragma unroll
    for (int s = 0; s < 4; s++) { p[s] = val[s] ? __expf(sc[s] - mx) : 0.f; lsum += p[s]; }
#pragma unroll
    for (int m = 1; m < 8; m <<= 1) lsum += __shfl_xor(lsum, m, 64);
    const float inv = 1.f / lsum;

    float out[DH];
#pragma unroll
    for (int d = 0; d < DH; d++) out[d] = 0.f;
#pragma unroll
    for (int s = 0; s < 4; s++) {
        if (val[s]) {
            float a = p[s] * inv;
            const float* vp = Vs + (kr[s] * 32 + kx[s]) * DH;
#pragma unroll
            for (int d = 0; d < DH; d++) out[d] += a * vp[d];
        }
    }
#pragma unroll
    for (int d = 0; d < DH; d++)
#pragma unroll
        for (int m = 1; m < 8; m <<= 1) out[d] += __shfl_xor(out[d], m, 64);

    const int l = y * Lw + qx;
    unsigned pk = (unsigned)f2b(out[sub * 2]) | ((unsigned)f2b(out[sub * 2 + 1]) << 16);
    *(unsigned*)(O + (size_t)(l * BN + n) * EE + h * DH + sub * 2) = pk;
}

// ---------------------------------------------------------------------------
// Launch
// ---------------------------------------------------------------------------
extern "C" void kernel_launch(void* const* d_in, const int* in_sizes, int n_in,
                              void* d_out, int out_size, void* d_ws, size_t ws_size,
                              hipStream_t stream)
{
    const float* buffer   = (const float*)d_in[0];
    const float* spa      = (const float*)d_in[1];
    const float* w_mlp    = (const float*)d_in[2];
    const float* ln1_g    = (const float*)d_in[3];
    const float* ln1_b    = (const float*)d_in[4];
    const float* in_proj  = (const float*)d_in[5];
    const float* out_proj = (const float*)d_in[6];
    const float* ln2_g    = (const float*)d_in[7];
    const float* ln2_b    = (const float*)d_in[8];
    const float* ff_w1    = (const float*)d_in[9];
    const float* ff_w2    = (const float*)d_in[10];
    const float* conv_w   = (const float*)d_in[11];
    float* out = (float*)d_out;

    char* ws = (char*)d_ws;
    // Workspace layout (bytes) — max live ~59.4 MB:
    float*  TOK  = (float*)(ws);                         // 13,107,200  residual, fp32
    float*  XS   = (float*)(ws + 13107200);              // 13,107,200  tok+pe fp32
    ushort* XLN2 = (ushort*)(ws + 13107200);             //   (reuse)   ln2 out bf16
    ushort* QKb  = (ushort*)(ws + 26214400);             // 13,107,200  q|k bf16 [m][256]
    ushort* FF   = (ushort*)(ws + 26214400);             //   (reuse)   ff1 out bf16 [m][256]
    ushort* Vb   = (ushort*)(ws + 39321600);             //  6,553,600  v bf16
    ushort* XLN  = (ushort*)(ws + 45875200);             //  6,553,600  ln1 out bf16
    ushort* AO   = (ushort*)(ws + 45875200);             //   (reuse)   attn out bf16
    ushort* Tbf  = (ushort*)(ws + 52428800);             //  3,276,800
    ushort* Sbf  = (ushort*)(ws + 55705600);             //  3,276,800
    ushort* Wb   = (ushort*)(ws + 58982400);             //    425,984  all weights bf16

    // 1. weight cast/reorder + input layout transform
    k_prep_w<<<dim3((W_TOTAL + 255) / 256), 256, 0, stream>>>(
        w_mlp, in_proj, out_proj, ff_w1, ff_w2, conv_w, Wb);
    k_prep_in<<<dim3(BN, Lh), 256, 0, stream>>>(buffer, spa, Tbf, Sbf);
    // 2. token embed (MFMA): TOK fp32, XS fp32
    k_token_mfma<<<dim3(BN, Lh), 256, 0, stream>>>(Tbf, Sbf, Wb + OFF_W2, TOK, XS);
    // 3. ln1: XS -> XLN bf16
    k_ln_bf<<<dim3(MROWS / 4), 256, 0, stream>>>(XS, ln1_g, ln1_b, XLN);
    // 4. q|k fused (N=256) from XLN; v from TOK
    k_mgemm<4, true ><<<dim3(200, 4), 256, 0, stream>>>(XLN, Wb + OFF_WQK, nullptr, QKb, MROWS, 256, EE);
    k_mgemm<4, false><<<dim3(200, 2), 256, 0, stream>>>(TOK, Wb + OFF_WV,  nullptr, Vb,  MROWS, EE, EE);
    // 5. local attention -> AO bf16
    k_attn<<<dim3(Lh, BN * NHD), 256, 0, stream>>>(QKb, Vb, AO);
    // 6. out_proj + residual: TOK = AO @ WO^T + TOK
    k_mgemm<2, true ><<<dim3(200, 2), 256, 0, stream>>>(AO, Wb + OFF_WO, TOK, TOK, MROWS, EE, EE);
    // 7. ln2: TOK -> XLN2 bf16
    k_ln_bf<<<dim3(MROWS / 4), 256, 0, stream>>>(TOK, ln2_g, ln2_b, XLN2);
    // 8. ff1 + relu -> FF bf16 (N=256)
    k_mgemm<1, true ><<<dim3(200, 4), 256, 0, stream>>>(XLN2, Wb + OFF_W1, nullptr, FF, MROWS, FFD, EE);
    // 9. ff2 + residual: TOK = FF @ W2f^T + TOK (K=256)
    k_mgemm<2, true ><<<dim3(200, 2), 256, 0, stream>>>(FF, Wb + OFF_W2F, TOK, TOK, MROWS, EE, FFD);
    // 10. conv + scatter to output layout
    k_mgemm<3, false><<<dim3(200, 1), 256, 0, stream>>>(TOK, Wb + OFF_WC, nullptr, out, MROWS, CC, EE);
}

// Round 3
// 206.632 us; speedup vs baseline: 2.2666x; 1.0845x over previous
//
#include <hip/hip_runtime.h>
#include <math.h>

// SpaTrans on MI355X. R3: MFMA attention (S^T trick: C-frag of K*Q^T == B-frag
// of PV under a key permutation), QKV in [n][h][l][d], LN1 fused into token.
#define Lh 32
#define Lw 32
#define LL 1024
#define BN 25
#define EE 128
#define CC 64
#define NHD 8
#define DH 16
#define FFD 256
#define MROWS 25600

typedef __attribute__((ext_vector_type(8))) short short8;
typedef __attribute__((ext_vector_type(4))) float f32x4;

__device__ inline ushort f2b(float x) {
    union { float f; unsigned u; } v; v.f = x;
    unsigned r = (v.u + 0x7fffu + ((v.u >> 16) & 1u)) >> 16;
    return (ushort)r;
}

// ---------------------------------------------------------------------------
// Weight prep (unchanged from R2)
// ---------------------------------------------------------------------------
#define OFF_W2  0
#define OFF_WQK 73728
#define OFF_WV  106496
#define OFF_WO  122880
#define OFF_W1  139264
#define OFF_W2F 172032
#define OFF_WC  204800
#define W_TOTAL 212992

__global__ __launch_bounds__(256) void k_prep_w(
    const float* __restrict__ w_mlp, const float* __restrict__ in_proj,
    const float* __restrict__ out_proj, const float* __restrict__ ff_w1,
    const float* __restrict__ ff_w2, const float* __restrict__ conv_w,
    ushort* __restrict__ Wb)
{
    int i = blockIdx.x * 256 + threadIdx.x;
    if (i >= W_TOTAL) return;
    if (i < 73728) {
        int e = i / 576, k = i - e * 576;
        int tap = k >> 6, ch = k & 63;
        Wb[OFF_W2 + i] = f2b(w_mlp[e * 576 + ch * 9 + tap]);
        return;
    }
    i -= 73728;
    if (i < 32768) { Wb[OFF_WQK + i] = f2b(in_proj[i]); return; }
    i -= 32768;
    if (i < 16384) { Wb[OFF_WV + i] = f2b(in_proj[32768 + i]); return; }
    i -= 16384;
    if (i < 16384) { Wb[OFF_WO + i] = f2b(out_proj[i]); return; }
    i -= 16384;
    if (i < 32768) { Wb[OFF_W1 + i] = f2b(ff_w1[i]); return; }
    i -= 32768;
    if (i < 32768) { Wb[OFF_W2F + i] = f2b(ff_w2[i]); return; }
    i -= 32768;
    Wb[OFF_WC + i] = f2b(conv_w[i]);
}

// ---------------------------------------------------------------------------
// Input prep (unchanged from R2)
// ---------------------------------------------------------------------------
__global__ __launch_bounds__(256) void k_prep_in(
    const float* __restrict__ buf, const float* __restrict__ spa,
    ushort* __restrict__ T, ushort* __restrict__ S)
{
    const int n = blockIdx.x, y = blockIdx.y;
    __shared__ float t0[64][33];
    __shared__ float t1[64][33];
    const int t = threadIdx.x;
    {
        int ch = t >> 2, x8 = (t & 3) * 8;
        const float* p = buf + ((size_t)(ch * BN + n) * LL + y * Lw + x8);
        const float* q = spa + ((size_t)(ch * BN + n) * LL + y * Lw + x8);
        float4 a0 = ((const float4*)p)[0], a1 = ((const float4*)p)[1];
        float4 b0 = ((const float4*)q)[0], b1 = ((const float4*)q)[1];
        float* d0 = &t0[ch][x8];
        float* d1 = &t1[ch][x8];
        d0[0] = a0.x; d0[1] = a0.y; d0[2] = a0.z; d0[3] = a0.w;
        d0[4] = a1.x; d0[5] = a1.y; d0[6] = a1.z; d0[7] = a1.w;
        d1[0] = a0.x + b0.x; d1[1] = a0.y + b0.y; d1[2] = a0.z + b0.z; d1[3] = a0.w + b0.w;
        d1[4] = a1.x + b1.x; d1[5] = a1.y + b1.y; d1[6] = a1.z + b1.z; d1[7] = a1.w + b1.w;
    }
    __syncthreads();
    {
        int x = t >> 3, c8 = (t & 7) * 8;
        union { ushort u[8]; uint4 v; } o0, o1;
#pragma unroll
        for (int j = 0; j < 8; j++) { o0.u[j] = f2b(t0[c8 + j][x]); o1.u[j] = f2b(t1[c8 + j][x]); }
        size_t base = (((size_t)n * Lh + y) * Lw + x) * 64 + c8;
        *(uint4*)(T + base) = o0.v;
        *(uint4*)(S + base) = o1.v;
    }
}

// ---------------------------------------------------------------------------
// Token embed via MFMA + fused LN1.
// TOK fp32 (residual); XLN = bf16 LN(tok+pe).
// ---------------------------------------------------------------------------
__global__ __launch_bounds__(256) void k_token_mfma(
    const ushort* __restrict__ T, const ushort* __restrict__ S,
    const ushort* __restrict__ W2, const float* __restrict__ g1,
    const float* __restrict__ b1, float* __restrict__ tok,
    ushort* __restrict__ XLN)
{
    const int n = blockIdx.x, y = blockIdx.y;
    __shared__ ushort At[3 * 34 * 72];
    __shared__ ushort As_[3 * 34 * 72];
    __shared__ float2 red[32][4];
    const int t = threadIdx.x;
    const uint4 z = make_uint4(0, 0, 0, 0);

    {
        int x = t >> 3, c8 = (t & 7) * 8;
#pragma unroll
        for (int dy = 0; dy < 3; dy++) {
            int yy = y + dy - 1;
            uint4 va = z, vs = z;
            if (yy >= 0 && yy < Lh) {
                size_t gi = (((size_t)n * Lh + yy) * Lw + x) * 64 + c8;
                va = *(const uint4*)(T + gi);
                vs = *(const uint4*)(S + gi);
            }
            *(uint4*)(At + (dy * 34 + x + 1) * 72 + c8) = va;
            *(uint4*)(As_ + (dy * 34 + x + 1) * 72 + c8) = vs;
        }
        if (t < 48) {
            int dy = t / 16, rem = t % 16;
            int colp = (rem >> 3) * 33, c8p = (rem & 7) * 8;
            *(uint4*)(At + (dy * 34 + colp) * 72 + c8p) = z;
            *(uint4*)(As_ + (dy * 34 + colp) * 72 + c8p) = z;
        }
    }
    __syncthreads();

    const int w = t >> 6, lane = t & 63;
    const int col = lane & 15, quad = lane >> 4;
    f32x4 accT[2][2] = {}, accS[2][2] = {};

    for (int tap = 0; tap < 9; tap++) {
        int dy = tap / 3, dx = tap % 3;
#pragma unroll
        for (int cc = 0; cc < 2; cc++) {
            int kg = tap * 64 + cc * 32 + quad * 8;
            short8 b0 = *(const short8*)(W2 + (size_t)(w * 32 + col) * 576 + kg);
            short8 bq = *(const short8*)(W2 + (size_t)(w * 32 + 16 + col) * 576 + kg);
            int abase = (dy * 34 + col + dx) * 72 + cc * 32 + quad * 8;
            short8 aT0 = *(const short8*)(At + abase);
            short8 aT1 = *(const short8*)(At + abase + 16 * 72);
            short8 aS0 = *(const short8*)(As_ + abase);
            short8 aS1 = *(const short8*)(As_ + abase + 16 * 72);
            accT[0][0] = __builtin_amdgcn_mfma_f32_16x16x32_bf16(aT0, b0, accT[0][0], 0, 0, 0);
            accT[0][1] = __builtin_amdgcn_mfma_f32_16x16x32_bf16(aT0, bq, accT[0][1], 0, 0, 0);
            accT[1][0] = __builtin_amdgcn_mfma_f32_16x16x32_bf16(aT1, b0, accT[1][0], 0, 0, 0);
            accT[1][1] = __builtin_amdgcn_mfma_f32_16x16x32_bf16(aT1, bq, accT[1][1], 0, 0, 0);
            accS[0][0] = __builtin_amdgcn_mfma_f32_16x16x32_bf16(aS0, b0, accS[0][0], 0, 0, 0);
            accS[0][1] = __builtin_amdgcn_mfma_f32_16x16x32_bf16(aS0, bq, accS[0][1], 0, 0, 0);
            accS[1][0] = __builtin_amdgcn_mfma_f32_16x16x32_bf16(aS1, b0, accS[1][0], 0, 0, 0);
            accS[1][1] = __builtin_amdgcn_mfma_f32_16x16x32_bf16(aS1, bq, accS[1][1], 0, 0, 0);
        }
    }

    // fused LN1: stage-1 per-wave partial sums over the 32 e's this wave owns
#pragma unroll
    for (int mi = 0; mi < 2; mi++)
#pragma unroll
        for (int r = 0; r < 4; r++) {
            float a0 = accS[mi][0][r], a1 = accS[mi][1][r];
            float ss = a0 + a1, qq = a0 * a0 + a1 * a1;
#pragma unroll
            for (int m = 1; m < 16; m <<= 1) {
                ss += __shfl_xor(ss, m, 64);
                qq += __shfl_xor(qq, m, 64);
            }
            if (col == 0) red[mi * 16 + quad * 4 + r][w] = make_float2(ss, qq);
        }
    __syncthreads();

    const float ga = g1[w * 32 + col],      ba = b1[w * 32 + col];
    const float gb = g1[w * 32 + 16 + col], bb = b1[w * 32 + 16 + col];
#pragma unroll
    for (int mi = 0; mi < 2; mi++)
#pragma unroll
        for (int r = 0; r < 4; r++) {
            int x = mi * 16 + quad * 4 + r;
            float2 p0 = red[x][0], p1 = red[x][1], p2 = red[x][2], p3 = red[x][3];
            float mean = (p0.x + p1.x + p2.x + p3.x) * (1.f / 128.f);
            float var  = (p0.y + p1.y + p2.y + p3.y) * (1.f / 128.f) - mean * mean;
            float rstd = rsqrtf(var + 1e-5f);
            size_t rowo = ((size_t)(y * Lw + x) * BN + n) * EE;
            int e0 = w * 32 + col, e1 = w * 32 + 16 + col;
            tok[rowo + e0] = accT[mi][0][r];
            tok[rowo + e1] = accT[mi][1][r];
            XLN[rowo + e0] = f2b((accS[mi][0][r] - mean) * rstd * ga + ba);
            XLN[rowo + e1] = f2b((accS[mi][1][r] - mean) * rstd * gb + bb);
        }
}

// ---------------------------------------------------------------------------
// LayerNorm (standalone, for ln2). bf16 out.
// ---------------------------------------------------------------------------
__global__ __launch_bounds__(256) void k_ln_bf(
    const float* __restrict__ in, const float* __restrict__ g,
    const float* __restrict__ b, ushort* __restrict__ out)
{
    int wave = threadIdx.x >> 6, lane = threadIdx.x & 63;
    int row = blockIdx.x * 4 + wave;
    const float2 v = ((const float2*)(in + (size_t)row * EE))[lane];
    float s = v.x + v.y, sq = v.x * v.x + v.y * v.y;
#pragma unroll
    for (int m = 1; m < 64; m <<= 1) {
        s  += __shfl_xor(s,  m, 64);
        sq += __shfl_xor(sq, m, 64);
    }
    float mean = s * (1.f / 128.f);
    float var  = sq * (1.f / 128.f) - mean * mean;
    float rstd = rsqrtf(var + 1e-5f);
    float2 gg = ((const float2*)g)[lane];
    float2 bb = ((const float2*)b)[lane];
    float ox = (v.x - mean) * rstd * gg.x + bb.x;
    float oy = (v.y - mean) * rstd * gg.y + bb.y;
    ((unsigned*)(out + (size_t)row * EE))[lane] = (unsigned)f2b(ox) | ((unsigned)f2b(oy) << 16);
}

// ---------------------------------------------------------------------------
// MFMA GEMM. MODE 1: relu->bf16 | 2: +R -> fp32 | 3: conv scatter fp32 |
// 5: QK scatter to Qh (Cp) / Kh (R cast) in [n][h][l][d] | 6: V scatter.
// ---------------------------------------------------------------------------
template <int MODE, bool ABF>
__global__ __launch_bounds__(256) void k_mgemm(
    const void* __restrict__ Ap, const ushort* __restrict__ Bw,
    const float* __restrict__ R, void* __restrict__ Cp,
    int M, int N, int K)
{
    __shared__ ushort As[128 * 40];
    __shared__ ushort Bs[64 * 40];
    const int m0 = blockIdx.x * 128, n0 = blockIdx.y * 64;
    const int t = threadIdx.x, w = t >> 6, lane = t & 63;
    const int col = lane & 15, quad = lane >> 4;
    f32x4 acc[2][4] = {};

    for (int k0 = 0; k0 < K; k0 += 32) {
        __syncthreads();
        {
            int nn = t >> 2, k8 = (t & 3) * 8;
            *(uint4*)(Bs + nn * 40 + k8) = *(const uint4*)(Bw + (size_t)(n0 + nn) * K + k0 + k8);
        }
        {
            int r = t >> 1, k16 = (t & 1) * 16;
            if (ABF) {
                const ushort* A = (const ushort*)Ap;
                const uint4* p = (const uint4*)(A + (size_t)(m0 + r) * K + k0 + k16);
                *(uint4*)(As + r * 40 + k16) = p[0];
                *(uint4*)(As + r * 40 + k16 + 8) = p[1];
            } else {
                const float* A = (const float*)Ap;
                const float4* p = (const float4*)(A + (size_t)(m0 + r) * K + k0 + k16);
                float4 f0 = p[0], f1 = p[1], f2 = p[2], f3 = p[3];
                union { ushort u[8]; uint4 v; } o0, o1;
                o0.u[0] = f2b(f0.x); o0.u[1] = f2b(f0.y); o0.u[2] = f2b(f0.z); o0.u[3] = f2b(f0.w);
                o0.u[4] = f2b(f1.x); o0.u[5] = f2b(f1.y); o0.u[6] = f2b(f1.z); o0.u[7] = f2b(f1.w);
                o1.u[0] = f2b(f2.x); o1.u[1] = f2b(f2.y); o1.u[2] = f2b(f2.z); o1.u[3] = f2b(f2.w);
                o1.u[4] = f2b(f3.x); o1.u[5] = f2b(f3.y); o1.u[6] = f2b(f3.z); o1.u[7] = f2b(f3.w);
                *(uint4*)(As + r * 40 + k16) = o0.v;
                *(uint4*)(As + r * 40 + k16 + 8) = o1.v;
            }
        }
        __syncthreads();
        short8 a0 = *(const short8*)(As + (w * 32 + col) * 40 + quad * 8);
        short8 a1 = *(const short8*)(As + (w * 32 + 16 + col) * 40 + quad * 8);
#pragma unroll
        for (int ni = 0; ni < 4; ni++) {
            short8 bf = *(const short8*)(Bs + (ni * 16 + col) * 40 + quad * 8);
            acc[0][ni] = __builtin_amdgcn_mfma_f32_16x16x32_bf16(a0, bf, acc[0][ni], 0, 0, 0);
            acc[1][ni] = __builtin_amdgcn_mfma_f32_16x16x32_bf16(a1, bf, acc[1][ni], 0, 0, 0);
        }
    }

#pragma unroll
    for (int mi = 0; mi < 2; mi++)
#pragma unroll
        for (int r = 0; r < 4; r++) {
            int m = m0 + w * 32 + mi * 16 + quad * 4 + r;
            int l = m / 25, bn = m - l * 25;
#pragma unroll
            for (int ni = 0; ni < 4; ni++) {
                int nn = n0 + ni * 16 + col;
                float v = acc[mi][ni][r];
                if (MODE == 1) {
                    ((ushort*)Cp)[(size_t)m * N + nn] = f2b(fmaxf(v, 0.f));
                } else if (MODE == 2) {
                    ((float*)Cp)[(size_t)m * N + nn] = v + R[(size_t)m * N + nn];
                } else if (MODE == 3) {
                    ((float*)Cp)[((size_t)nn * 25 + bn) * 1024 + l] = v;
                } else if (MODE == 5) {
                    ushort* dst = (nn < 128) ? (ushort*)Cp : (ushort*)(void*)R;
                    int hh = (nn & 127) >> 4, dd = nn & 15;
                    dst[((size_t)(bn * 8 + hh) * 1024 + l) * 16 + dd] = f2b(v);
                } else if (MODE == 6) {
                    ((ushort*)Cp)[((size_t)(bn * 8 + (nn >> 4)) * 1024 + l) * 16 + (nn & 15)] = f2b(v);
                }
            }
        }
}

// ---------------------------------------------------------------------------
// MFMA local-window attention. One wave per (y, n, h); 4 waves/block.
// S^T = K*Q^T (keys=M): C-frag (col=q, row=key) doubles as PV B-frag under
// key permutation pos = c*32 + quad*8 + i. V^T staged permuted in LDS.
// ---------------------------------------------------------------------------
__global__ __launch_bounds__(256) void k_attn(
    const ushort* __restrict__ Qh, const ushort* __restrict__ Kh,
    const ushort* __restrict__ Vh, ushort* __restrict__ AO)
{
    __shared__ ushort VT[4][16 * 168];
    const int t = threadIdx.x, w = t >> 6, lane = t & 63;
    const int col = lane & 15, quad = lane >> 4;
    const int wid = blockIdx.x * 4 + w;
    const int y = wid & 31, h = (wid >> 5) & 7, n = wid >> 8;
    const size_t base = (size_t)(n * 8 + h) * 1024;

    // stage V^T in permuted key order (wave-private; garbage rows masked by P=0)
    for (int i = lane; i < 160; i += 64) {
        int kr = i >> 5, kx = i & 31;
        int yyc = min(max(y - 2 + kr, 0), 31);
        const ushort* src = Vh + (base + yyc * 32 + kx) * 16;
        union { uint4 v; ushort u[8]; } ua, ub;
        ua.v = *(const uint4*)(src);
        ub.v = *(const uint4*)(src + 8);
        int pos = (kr << 5) + (((kx & 15) >> 2) << 3) + ((kx >> 4) << 2) + (kx & 3);
        ushort* dst = &VT[w][pos];
#pragma unroll
        for (int d = 0; d < 8; d++) dst[d * 168] = ua.u[d];
#pragma unroll
        for (int d = 0; d < 8; d++) dst[(d + 8) * 168] = ub.u[d];
    }

    // Q B-frags (K-dim padded 16->32: quads 2,3 hold zeros)
    short8 z8 = {0, 0, 0, 0, 0, 0, 0, 0};
    short8 qf[2] = { z8, z8 };
#pragma unroll
    for (int j = 0; j < 2; j++)
        if (quad < 2)
            qf[j] = *(const short8*)(Qh + (base + y * 32 + j * 16 + col) * 16 + quad * 8);

    // scores S^T: tile tt = kr*2 + half; A-frag = K rows (clamped)
    f32x4 S[2][10] = {};
#pragma unroll
    for (int tt = 0; tt < 10; tt++) {
        int kr = tt >> 1, kx = ((tt & 1) << 4) + col;
        int yyc = min(max(y - 2 + kr, 0), 31);
        short8 kf = z8;
        if (quad < 2)
            kf = *(const short8*)(Kh + (base + yyc * 32 + kx) * 16 + quad * 8);
        S[0][tt] = __builtin_amdgcn_mfma_f32_16x16x32_bf16(kf, qf[0], S[0][tt], 0, 0, 0);
        S[1][tt] = __builtin_amdgcn_mfma_f32_16x16x32_bf16(kf, qf[1], S[1][tt], 0, 0, 0);
    }

    // masked softmax (per q = j*16+col; keys spread over quads -> xor 16,32)
    float invs[2];
#pragma unroll
    for (int j = 0; j < 2; j++) {
        int qx = j * 16 + col;
        float mx = -1e30f;
#pragma unroll
        for (int tt = 0; tt < 10; tt++) {
            int yy = y - 2 + (tt >> 1);
            bool rok = (yy >= 0) && (yy < 32);
            int kxb = ((tt & 1) << 4) + quad * 4;
#pragma unroll
            for (int r = 0; r < 4; r++) {
                int dd = kxb + r - qx;
                bool ok = rok && ((unsigned)(dd + 2) <= 4u);
                float v = ok ? S[j][tt][r] * 0.25f : -1e30f;
                S[j][tt][r] = v;
                mx = fmaxf(mx, v);
            }
        }
        mx = fmaxf(mx, __shfl_xor(mx, 16, 64));
        mx = fmaxf(mx, __shfl_xor(mx, 32, 64));
        float sum = 0.f;
#pragma unroll
        for (int tt = 0; tt < 10; tt++)
#pragma unroll
            for (int r = 0; r < 4; r++) {
                float p = __expf(S[j][tt][r] - mx);
                S[j][tt][r] = p;
                sum += p;
            }
        sum += __shfl_xor(sum, 16, 64);
        sum += __shfl_xor(sum, 32, 64);
        invs[j] = 1.f / sum;
    }

    // PV: out^T[d][q] += V^T[d][pos] * P[q][pos]; B-frag = packed C-frag pairs
    f32x4 O[2] = {};
#pragma unroll
    for (int c = 0; c < 5; c++) {
        short8 vt = *(const short8*)(&VT[w][col * 168 + c * 32 + quad * 8]);
#pragma unroll
        for (int j = 0; j < 2; j++) {
            union { ushort u[8]; short8 s; } pb;
#pragma unroll
            for (int i = 0; i < 8; i++)
                pb.u[i] = f2b(S[j][2 * c + (i >> 2)][i & 3] * invs[j]);
            O[j] = __builtin_amdgcn_mfma_f32_16x16x32_bf16(vt, pb.s, O[j], 0, 0, 0);
        }
    }

    // store: lane holds q=col, d=quad*4+0..3 -> 8B per store, AO[l][n][e]
#pragma unroll
    for (int j = 0; j < 2; j++) {
        int l = y * Lw + j * 16 + col;
        ushort4 o;
        o.x = f2b(O[j][0]); o.y = f2b(O[j][1]); o.z = f2b(O[j][2]); o.w = f2b(O[j][3]);
        *(ushort4*)(AO + ((size_t)l * BN + n) * EE + h * DH + quad * 4) = o;
    }
}

// ---------------------------------------------------------------------------
// Launch
// ---------------------------------------------------------------------------
extern "C" void kernel_launch(void* const* d_in, const int* in_sizes, int n_in,
                              void* d_out, int out_size, void* d_ws, size_t ws_size,
                              hipStream_t stream)
{
    const float* buffer   = (const float*)d_in[0];
    const float* spa      = (const float*)d_in[1];
    const float* w_mlp    = (const float*)d_in[2];
    const float* ln1_g    = (const float*)d_in[3];
    const float* ln1_b    = (const float*)d_in[4];
    const float* in_proj  = (const float*)d_in[5];
    const float* out_proj = (const float*)d_in[6];
    const float* ln2_g    = (const float*)d_in[7];
    const float* ln2_b    = (const float*)d_in[8];
    const float* ff_w1    = (const float*)d_in[9];
    const float* ff_w2    = (const float*)d_in[10];
    const float* conv_w   = (const float*)d_in[11];
    float* out = (float*)d_out;

    char* ws = (char*)d_ws;
    float*  TOK  = (float*)(ws);                 // 13,107,200 fp32 residual
    ushort* XLN  = (ushort*)(ws + 13107200);     //  6,553,600 ln1 out bf16
    ushort* Qh   = (ushort*)(ws + 19660800);     //  6,553,600 [n][h][l][d]
    ushort* Kh   = (ushort*)(ws + 26214400);     //  6,553,600
    ushort* Vh   = (ushort*)(ws + 32768000);     //  6,553,600
    ushort* AO   = (ushort*)(ws + 39321600);     //  6,553,600 attn out [l][n][e]
    ushort* XLN2 = (ushort*)(ws + 45875200);     //  6,553,600 ln2 out bf16
    ushort* FF   = (ushort*)(ws + 52428800);     // 13,107,200 ff1 out bf16
    ushort* Tbf  = (ushort*)(ws + 65536000);     //  3,276,800
    ushort* Sbf  = (ushort*)(ws + 68812800);     //  3,276,800
    ushort* Wb   = (ushort*)(ws + 72089600);     //    425,984

    k_prep_w<<<dim3((W_TOTAL + 255) / 256), 256, 0, stream>>>(
        w_mlp, in_proj, out_proj, ff_w1, ff_w2, conv_w, Wb);
    k_prep_in<<<dim3(BN, Lh), 256, 0, stream>>>(buffer, spa, Tbf, Sbf);
    // token embed + fused LN1
    k_token_mfma<<<dim3(BN, Lh), 256, 0, stream>>>(Tbf, Sbf, Wb + OFF_W2,
                                                   ln1_g, ln1_b, TOK, XLN);
    // q|k fused (N=256) scatter to [n][h][l][d]; v from TOK
    k_mgemm<5, true ><<<dim3(200, 4), 256, 0, stream>>>(XLN, Wb + OFF_WQK, (const float*)(void*)Kh, Qh, MROWS, 256, EE);
    k_mgemm<6, false><<<dim3(200, 2), 256, 0, stream>>>(TOK, Wb + OFF_WV, nullptr, Vh, MROWS, EE, EE);
    // MFMA local attention
    k_attn<<<dim3(1600), 256, 0, stream>>>(Qh, Kh, Vh, AO);
    // out_proj + residual
    k_mgemm<2, true ><<<dim3(200, 2), 256, 0, stream>>>(AO, Wb + OFF_WO, TOK, TOK, MROWS, EE, EE);
    // ln2
    k_ln_bf<<<dim3(MROWS / 4), 256, 0, stream>>>(TOK, ln2_g, ln2_b, XLN2);
    // ff1 + relu
    k_mgemm<1, true ><<<dim3(200, 4), 256, 0, stream>>>(XLN2, Wb + OFF_W1, nullptr, FF, MROWS, FFD, EE);
    // ff2 + residual
    k_mgemm<2, true ><<<dim3(200, 2), 256, 0, stream>>>(FF, Wb + OFF_W2F, TOK, TOK, MROWS, EE, FFD);
    // conv + output scatter
    k_mgemm<3, false><<<dim3(200, 1), 256, 0, stream>>>(TOK, Wb + OFF_WC, nullptr, out, MROWS, CC, EE);
}